// Round 1
// baseline (1151.202 us; speedup 1.0000x reference)
//
#include <hip/hip_runtime.h>
#include <cstdint>
#include <cstddef>

#define B_ 8
#define C_ 256
#define CQ 32
#define N_ 4096

typedef __attribute__((ext_vector_type(8))) short bf16x8;
typedef __attribute__((ext_vector_type(4))) float f32x4;

__device__ __forceinline__ short f2bf(float f) {
    union { float f; uint32_t u; } v; v.f = f;
    uint32_t r = (v.u + 0x7FFFu + ((v.u >> 16) & 1u)) >> 16;   // RNE
    return (short)r;
}

// ---------------- K0: weights fp32 -> bf16 ----------------
__global__ __launch_bounds__(256) void wconv(const float* wq, const float* wk, const float* wv,
                                             short* wqb, short* wkb, short* wvb) {
    int i = blockIdx.x * 256 + threadIdx.x;        // grid 256 blocks -> 65536 threads
    if (i < 8192) { wqb[i] = f2bf(wq[i]); wkb[i] = f2bf(wk[i]); }
    if (i < 65536) wvb[i] = f2bf(wv[i]);
}

// ---------------- K1: x[b][c][n] -> xb_t[b][n][c] (bf16) ----------------
__global__ __launch_bounds__(256) void xpose(const float* x, short* xbt) {
    int blk = blockIdx.x;            // 8 * 128 * 8 = 8192 blocks
    int b = blk >> 10;
    int rem = blk & 1023;
    int nt = rem >> 3, ct = rem & 7;
    int n0 = nt * 32, c0 = ct * 32;
    __shared__ short tile[32][33];
    int tx = threadIdx.x & 31, ty = threadIdx.x >> 5;    // ty 0..7
    const float* xb = x + (size_t)b * C_ * N_;
#pragma unroll
    for (int i = 0; i < 4; i++) {
        int c = c0 + ty + i * 8;
        tile[ty + i * 8][tx] = f2bf(xb[(size_t)c * N_ + n0 + tx]);
    }
    __syncthreads();
    short* dst = xbt + (size_t)b * N_ * C_;
#pragma unroll
    for (int i = 0; i < 4; i++) {
        int n = n0 + ty + i * 8;
        dst[(size_t)n * C_ + c0 + tx] = tile[tx][ty + i * 8];
    }
}

// ---------------- K2: q/k projection -> q_t/k_t [b][n][32] bf16 ----------------
// wave-tile: 16 n-rows x 32 cq, for BOTH q and k. K = 256 (8 MFMA steps each).
__global__ __launch_bounds__(256) void qkproj(const short* xbt, const short* wqb, const short* wkb,
                                              const float* bq, const float* bk,
                                              short* qt, short* kt) {
    int w = threadIdx.x >> 6, lane = threadIdx.x & 63;
    int gw = blockIdx.x * 4 + w;          // 2048 waves = 8 b * 256 n-tiles
    int b = gw >> 8, nt = gw & 255;
    int n0 = nt * 16;
    int col = lane & 15, quad = lane >> 4;
    const bf16x8* arow = (const bf16x8*)(xbt + ((size_t)(b * N_ + n0 + col)) * C_ + quad * 8);
    const bf16x8* q0p = (const bf16x8*)(wqb + (size_t)col * C_ + quad * 8);
    const bf16x8* q1p = (const bf16x8*)(wqb + (size_t)(16 + col) * C_ + quad * 8);
    const bf16x8* k0p = (const bf16x8*)(wkb + (size_t)col * C_ + quad * 8);
    const bf16x8* k1p = (const bf16x8*)(wkb + (size_t)(16 + col) * C_ + quad * 8);
    f32x4 aq0 = {0,0,0,0}, aq1 = {0,0,0,0}, ak0 = {0,0,0,0}, ak1 = {0,0,0,0};
#pragma unroll
    for (int ks = 0; ks < 8; ks++) {
        bf16x8 a = arow[ks * 4];          // +32 shorts per k-step
        aq0 = __builtin_amdgcn_mfma_f32_16x16x32_bf16(a, q0p[ks * 4], aq0, 0, 0, 0);
        aq1 = __builtin_amdgcn_mfma_f32_16x16x32_bf16(a, q1p[ks * 4], aq1, 0, 0, 0);
        ak0 = __builtin_amdgcn_mfma_f32_16x16x32_bf16(a, k0p[ks * 4], ak0, 0, 0, 0);
        ak1 = __builtin_amdgcn_mfma_f32_16x16x32_bf16(a, k1p[ks * 4], ak1, 0, 0, 0);
    }
    float bq0 = bq[col], bq1 = bq[16 + col], bk0 = bk[col], bk1 = bk[16 + col];
#pragma unroll
    for (int r = 0; r < 4; r++) {
        int n = n0 + quad * 4 + r;        // D row = quad*4+reg
        size_t base = ((size_t)b * N_ + n) * CQ;
        qt[base + col]      = f2bf(aq0[r] + bq0);
        qt[base + 16 + col] = f2bf(aq1[r] + bq1);
        kt[base + col]      = f2bf(ak0[r] + bk0);
        kt[base + 16 + col] = f2bf(ak1[r] + bk1);
    }
}

// ---------------- K3: v projection -> v[b][c][n] bf16 ----------------
// wave-tile: 16 c x 64 n. A = Wv (row-major), B^T = xb_t.
__global__ __launch_bounds__(256) void vproj(const short* xbt, const short* wvb,
                                             const float* bv, short* vb) {
    int w = threadIdx.x >> 6, lane = threadIdx.x & 63;
    int gw = blockIdx.x * 4 + w;          // 8192 waves = 8 * 16 * 64
    int b = gw >> 10;
    int rem = gw & 1023;
    int ct = rem >> 6, nt = rem & 63;
    int c0 = ct * 16, n0 = nt * 64;
    int col = lane & 15, quad = lane >> 4;
    const bf16x8* arow = (const bf16x8*)(wvb + (size_t)(c0 + col) * C_ + quad * 8);
    const bf16x8* brow[4];
#pragma unroll
    for (int j = 0; j < 4; j++)
        brow[j] = (const bf16x8*)(xbt + ((size_t)b * N_ + n0 + j * 16 + col) * C_ + quad * 8);
    f32x4 acc[4];
#pragma unroll
    for (int j = 0; j < 4; j++) acc[j] = (f32x4){0,0,0,0};
#pragma unroll
    for (int ks = 0; ks < 8; ks++) {
        bf16x8 a = arow[ks * 4];
#pragma unroll
        for (int j = 0; j < 4; j++)
            acc[j] = __builtin_amdgcn_mfma_f32_16x16x32_bf16(a, brow[j][ks * 4], acc[j], 0, 0, 0);
    }
#pragma unroll
    for (int r = 0; r < 4; r++) {
        int c = c0 + quad * 4 + r;
        float bias = bv[c];
        size_t base = ((size_t)b * C_ + c) * N_ + n0;
#pragma unroll
        for (int j = 0; j < 4; j++)
            vb[base + j * 16 + col] = f2bf(acc[j][r] + bias);
    }
}

// ---------------- K4: energy[b][n][m] = q_t . k_t  (K=32, one MFMA/tile) ----------------
__global__ __launch_bounds__(256) void energy_k(const short* qt, const short* kt, float* attn) {
    int w = threadIdx.x >> 6, lane = threadIdx.x & 63;
    int gw = blockIdx.x * 4 + w;          // 32768 waves = 8 * 64 * 64
    int b = gw >> 12;
    int rem = gw & 4095;
    int nt = rem >> 6, mt = rem & 63;
    int n0 = nt * 64, m0 = mt * 64;
    int col = lane & 15, quad = lane >> 4;
    bf16x8 a[4], bb[4];
#pragma unroll
    for (int i = 0; i < 4; i++)
        a[i] = *(const bf16x8*)(qt + ((size_t)b * N_ + n0 + i * 16 + col) * CQ + quad * 8);
#pragma unroll
    for (int j = 0; j < 4; j++)
        bb[j] = *(const bf16x8*)(kt + ((size_t)b * N_ + m0 + j * 16 + col) * CQ + quad * 8);
    float* base = attn + (size_t)b * N_ * N_;
    f32x4 zero = {0,0,0,0};
#pragma unroll
    for (int i = 0; i < 4; i++) {
#pragma unroll
        for (int j = 0; j < 4; j++) {
            f32x4 acc = __builtin_amdgcn_mfma_f32_16x16x32_bf16(a[i], bb[j], zero, 0, 0, 0);
#pragma unroll
            for (int r = 0; r < 4; r++)
                base[(size_t)(n0 + i * 16 + quad * 4 + r) * N_ + m0 + j * 16 + col] = acc[r];
        }
    }
}

// ---------------- K5: row softmax in place ----------------
__global__ __launch_bounds__(256) void softmax_k(float* attn) {
    size_t row = blockIdx.x;              // 32768 rows
    float* p = attn + row * (size_t)N_;
    int t = threadIdx.x;
    f32x4 v[4];
#pragma unroll
    for (int j = 0; j < 4; j++) v[j] = ((const f32x4*)p)[t + j * 256];
    float m = -1e30f;
#pragma unroll
    for (int j = 0; j < 4; j++) {
        m = fmaxf(m, fmaxf(fmaxf(v[j].x, v[j].y), fmaxf(v[j].z, v[j].w)));
    }
#pragma unroll
    for (int off = 32; off > 0; off >>= 1) m = fmaxf(m, __shfl_xor(m, off, 64));
    __shared__ float sred[8];
    int w = t >> 6, lane = t & 63;
    if (lane == 0) sred[w] = m;
    __syncthreads();
    m = fmaxf(fmaxf(sred[0], sred[1]), fmaxf(sred[2], sred[3]));
    float s = 0.f;
#pragma unroll
    for (int j = 0; j < 4; j++) {
        v[j].x = __expf(v[j].x - m); v[j].y = __expf(v[j].y - m);
        v[j].z = __expf(v[j].z - m); v[j].w = __expf(v[j].w - m);
        s += v[j].x + v[j].y + v[j].z + v[j].w;
    }
#pragma unroll
    for (int off = 32; off > 0; off >>= 1) s += __shfl_xor(s, off, 64);
    if (lane == 0) sred[4 + w] = s;
    __syncthreads();
    s = sred[4] + sred[5] + sred[6] + sred[7];
    float inv = 1.0f / s;
#pragma unroll
    for (int j = 0; j < 4; j++) ((f32x4*)p)[t + j * 256] = v[j] * inv;
}

// ---------------- K6: out[b][c][n] = 0.5*gamma*(v @ attn^T) + x ----------------
// block = 4 waves; block-tile 256c x 64n; k-loop over m staging attn->bf16 in LDS.
__global__ __launch_bounds__(256) void pv_blend(const short* vb, const float* attn,
                                                const float* x, const float* gamma, float* out) {
    int blk = blockIdx.x;                 // 512 = 8 b * 64 n-tiles
    int b = blk >> 6, nt = blk & 63;
    int n0 = nt * 64;
    int t = threadIdx.x;
    int w = t >> 6, lane = t & 63;
    int col = lane & 15, quad = lane >> 4;
    int c0 = w * 64;
    __shared__ short sB[64 * 40];         // 64 rows x 32 k, stride 40 (16B-aligned, ~2-way banks)
    const float* abase = attn + ((size_t)b * N_ + n0) * N_;
    int srow = t >> 2, sch = t & 3;
    const float* sp = abase + (size_t)srow * N_ + sch * 8;
    short* sdst = sB + srow * 40 + sch * 8;
    const bf16x8* arow[4];
#pragma unroll
    for (int i = 0; i < 4; i++)
        arow[i] = (const bf16x8*)(vb + ((size_t)b * C_ + c0 + i * 16 + col) * N_ + quad * 8);
    f32x4 acc[4][4];
#pragma unroll
    for (int i = 0; i < 4; i++)
#pragma unroll
        for (int j = 0; j < 4; j++) acc[i][j] = (f32x4){0,0,0,0};

    for (int k0 = 0; k0 < N_; k0 += 32) {
        f32x4 t0 = *(const f32x4*)(sp + k0);
        f32x4 t1 = *(const f32x4*)(sp + k0 + 4);
        bf16x8 pk;
        pk[0] = f2bf(t0.x); pk[1] = f2bf(t0.y); pk[2] = f2bf(t0.z); pk[3] = f2bf(t0.w);
        pk[4] = f2bf(t1.x); pk[5] = f2bf(t1.y); pk[6] = f2bf(t1.z); pk[7] = f2bf(t1.w);
        *(bf16x8*)sdst = pk;
        __syncthreads();
        bf16x8 bfr[4];
#pragma unroll
        for (int j = 0; j < 4; j++)
            bfr[j] = *(const bf16x8*)(sB + (j * 16 + col) * 40 + quad * 8);
        int ku = k0 >> 3;                 // short8 units
#pragma unroll
        for (int i = 0; i < 4; i++) {
            bf16x8 a = arow[i][ku];
#pragma unroll
            for (int j = 0; j < 4; j++)
                acc[i][j] = __builtin_amdgcn_mfma_f32_16x16x32_bf16(a, bfr[j], acc[i][j], 0, 0, 0);
        }
        __syncthreads();
    }
    float g = 0.5f * gamma[0];            // sigma*(gamma*o + x) + (1-sigma)*x = 0.5*gamma*o + x
#pragma unroll
    for (int i = 0; i < 4; i++) {
#pragma unroll
        for (int r = 0; r < 4; r++) {
            int c = c0 + i * 16 + quad * 4 + r;
            size_t base = ((size_t)b * C_ + c) * N_ + n0;
#pragma unroll
            for (int j = 0; j < 4; j++) {
                int n = j * 16 + col;
                out[base + n] = g * acc[i][j][r] + x[base + n];
            }
        }
    }
}

extern "C" void kernel_launch(void* const* d_in, const int* in_sizes, int n_in,
                              void* d_out, int out_size, void* d_ws, size_t ws_size,
                              hipStream_t stream) {
    const float* x     = (const float*)d_in[0];
    const float* Wq    = (const float*)d_in[1];
    const float* bq    = (const float*)d_in[2];
    const float* Wk    = (const float*)d_in[3];
    const float* bk    = (const float*)d_in[4];
    const float* Wv    = (const float*)d_in[5];
    const float* bv    = (const float*)d_in[6];
    const float* gamma = (const float*)d_in[7];
    float* out  = (float*)d_out;
    float* attn = out + (size_t)B_ * C_ * N_;     // attention follows out, flat

    char* ws = (char*)d_ws;                       // ~38 MB used, fully rewritten each call
    short* xbt = (short*)(ws);                    // [B][N][C]  16 MB
    short* qt  = (short*)(ws + 16777216);         // [B][N][32]  2 MB
    short* kt  = (short*)(ws + 18874368);         // [B][N][32]  2 MB
    short* vb  = (short*)(ws + 20971520);         // [B][C][N]  16 MB
    short* wqb = (short*)(ws + 37748736);
    short* wkb = (short*)(ws + 37765120);
    short* wvb = (short*)(ws + 37781504);

    hipLaunchKernelGGL(wconv,    dim3(256),   dim3(256), 0, stream, Wq, Wk, Wv, wqb, wkb, wvb);
    hipLaunchKernelGGL(xpose,    dim3(8192),  dim3(256), 0, stream, x, xbt);
    hipLaunchKernelGGL(qkproj,   dim3(512),   dim3(256), 0, stream, xbt, wqb, wkb, bq, bk, qt, kt);
    hipLaunchKernelGGL(vproj,    dim3(2048),  dim3(256), 0, stream, xbt, wvb, bv, vb);
    hipLaunchKernelGGL(energy_k, dim3(8192),  dim3(256), 0, stream, qt, kt, attn);
    hipLaunchKernelGGL(softmax_k,dim3(32768), dim3(256), 0, stream, attn);
    hipLaunchKernelGGL(pv_blend, dim3(512),   dim3(256), 0, stream, vb, attn, x, gamma, out);
}